// Round 11
// baseline (272.993 us; speedup 1.0000x reference)
//
#include <hip/hip_runtime.h>
#include <hip/hip_bf16.h>

typedef __hip_bfloat16 bf16;
typedef __attribute__((ext_vector_type(8))) short short8;
typedef __attribute__((ext_vector_type(4))) float f32x4;

#define Bq   2
#define Tq   2048
#define Dq   2048
#define NHq  16
#define HDq  48
#define LATq 256
#define NLHq 8
#define QN   (NHq * HDq)    // 768
#define KVN  (NLHq * HDq)   // 384

__device__ __forceinline__ unsigned short f2u(float x) {
    __hip_bfloat16 h = __float2bfloat16(x);
    return *reinterpret_cast<unsigned short*>(&h);
}
__device__ __forceinline__ float u2f(unsigned short u) {
    return __uint_as_float((unsigned)u << 16);
}
__device__ __forceinline__ unsigned pk2(float a, float b) {
    return (unsigned)f2u(a) | ((unsigned)f2u(b) << 16);
}

// ---- x fp32 -> bf16, 8 elems/thread ------------------------------------------
__global__ void __launch_bounds__(256)
cvt_x(const float* __restrict__ in, bf16* __restrict__ out) {
    const size_t i = ((size_t)blockIdx.x * 256 + threadIdx.x) * 8;
    const float4 a = *(const float4*)&in[i];
    const float4 b = *(const float4*)&in[i + 4];
    uint4 u;
    u.x = pk2(a.x, a.y); u.y = pk2(a.z, a.w);
    u.z = pk2(b.x, b.y); u.w = pk2(b.z, b.w);
    *(uint4*)&out[i] = u;
}

// ---- W fp32 [K][N] -> WT bf16 [N][K], 32x32 LDS tiles -------------------------
__global__ void __launch_bounds__(256)
tr_w(const float* __restrict__ W, bf16* __restrict__ WT, int K, int N) {
    __shared__ float ts[32][33];
    const int n0 = blockIdx.x * 32, k0 = blockIdx.y * 32;
    const int t = threadIdx.x;
    const int r = t >> 3, c4 = (t & 7) * 4;
    const float4 v = *(const float4*)&W[(size_t)(k0 + r) * N + n0 + c4];
    ts[r][c4] = v.x; ts[r][c4 + 1] = v.y; ts[r][c4 + 2] = v.z; ts[r][c4 + 3] = v.w;
    __syncthreads();
    const unsigned u0 = pk2(ts[c4][r], ts[c4 + 1][r]);
    const unsigned u1 = pk2(ts[c4 + 2][r], ts[c4 + 3][r]);
    *(uint2*)&WT[(size_t)(n0 + r) * K + k0 + c4] = make_uint2(u0, u1);
}

// ==== bf16 GEMM, 64x64 tile, double-buffered LDS, 1 barrier/k-step ============
// R10 had 128x64 tiles -> grids 384-1024, only 2 blocks/CU for the fused-qkv
// GEMM (8 waves/CU: latency chains exposed, ~230 TF). Same lesson as attn
// R8->R10: more waves/CU with staging amortization intact. 64x64 tile, 4 waves
// (2x2), BK=32, register-prefetch + one barrier per k-step (R8's proven glo/
// lwrite skeleton). Grids 1024/768/2048 = 4-8 blocks/CU. LDS 20.5KB; ~60 VGPR.
// Shrinking M-tile does NOT duplicate A staging; extra BT passes L2-resident.
// Epilogue by MODE (64-col tiles never straddle the split points):
//   0: N=1024 fused qkv  -> col<768: q bf16 [.][768]; else xkv fp32 [.][256]
//   1: N=768  fused k|v  -> col<384: k bf16 [.][384]; else v bf16 [.][384]
//   2: N=2048 oproj      -> fp32 [.][2048]
template<int MODE>
__global__ void __launch_bounds__(256)
gemm64(const bf16* __restrict__ A, const bf16* __restrict__ BT,
       void* __restrict__ C0v, void* __restrict__ C1v, int K) {
    __shared__ short As[2][64 * 40];
    __shared__ short Bs[2][64 * 40];
    const int t  = threadIdx.x;
    const int m0 = blockIdx.x * 64;
    const int n0 = blockIdx.y * 64;
    const int w  = t >> 6;
    const int wm = (w & 1) * 32;
    const int wn = (w >> 1) * 32;
    const int lr = t & 15;
    const int quad = (t >> 4) & 3;
    const int sr = t >> 2, sc = t & 3;          // staging row / 16B chunk

    f32x4 acc[2][2];
    #pragma unroll
    for (int mi = 0; mi < 2; ++mi)
        #pragma unroll
        for (int ni = 0; ni < 2; ++ni) acc[mi][ni] = (f32x4){0.f, 0.f, 0.f, 0.f};

    int aoff[2], boff[2];
    #pragma unroll
    for (int mi = 0; mi < 2; ++mi) aoff[mi] = (wm + mi * 16 + lr) * 40 + quad * 8;
    #pragma unroll
    for (int ni = 0; ni < 2; ++ni) boff[ni] = (wn + ni * 16 + lr) * 40 + quad * 8;

    uint4 pa0, pb0;
    auto glo = [&](int kt) {
        const int kb = kt * 32 + sc * 8;
        pa0 = *(const uint4*)&A[(size_t)(m0 + sr) * K + kb];
        pb0 = *(const uint4*)&BT[(size_t)(n0 + sr) * K + kb];
    };
    auto lwrite = [&](int bb) {
        *(uint4*)&As[bb][sr * 40 + sc * 8] = pa0;
        *(uint4*)&Bs[bb][sr * 40 + sc * 8] = pb0;
    };

    const int nk = K / 32;
    glo(0);
    lwrite(0);
    __syncthreads();
    int cur = 0;

    for (int kt = 0; kt < nk; ++kt) {
        const bool pref = (kt + 1 < nk);
        if (pref) glo(kt + 1);
        short8 af[2], bfr[2];
        #pragma unroll
        for (int mi = 0; mi < 2; ++mi) af[mi] = *(const short8*)&As[cur][aoff[mi]];
        #pragma unroll
        for (int ni = 0; ni < 2; ++ni) bfr[ni] = *(const short8*)&Bs[cur][boff[ni]];
        #pragma unroll
        for (int mi = 0; mi < 2; ++mi)
            #pragma unroll
            for (int ni = 0; ni < 2; ++ni)
                acc[mi][ni] = __builtin_amdgcn_mfma_f32_16x16x32_bf16(af[mi], bfr[ni], acc[mi][ni], 0, 0, 0);
        if (pref) lwrite(cur ^ 1);
        __syncthreads();
        cur ^= 1;
    }

    #pragma unroll
    for (int mi = 0; mi < 2; ++mi)
        #pragma unroll
        for (int ni = 0; ni < 2; ++ni) {
            const int col = n0 + wn + ni * 16 + lr;
            #pragma unroll
            for (int r = 0; r < 4; ++r) {
                const int row = m0 + wm + mi * 16 + quad * 4 + r;
                const float v = acc[mi][ni][r];
                if constexpr (MODE == 0) {
                    if (col < QN) ((bf16*)C0v)[(size_t)row * QN + col] = __float2bfloat16(v);
                    else ((float*)C1v)[(size_t)row * LATq + (col - QN)] = v;
                } else if constexpr (MODE == 1) {
                    if (col < KVN) ((bf16*)C0v)[(size_t)row * KVN + col] = __float2bfloat16(v);
                    else ((bf16*)C1v)[(size_t)row * KVN + (col - KVN)] = __float2bfloat16(v);
                } else {
                    ((float*)C0v)[(size_t)row * Dq + col] = v;
                }
            }
        }
}

// ---- lat = rmsnorm(xkv)*wn : [4096,256]fp32 -> bf16. 1 wave per row. ----------
__global__ void __launch_bounds__(256)
mla_kvrms(const float* __restrict__ xkv, const float* __restrict__ wn,
          bf16* __restrict__ lat) {
    const int t = threadIdx.x;
    const int row = blockIdx.x * 4 + (t >> 6);
    const int lane = t & 63;
    const float4 v = *(const float4*)&xkv[(size_t)row * LATq + lane * 4];
    float ss = v.x * v.x + v.y * v.y + v.z * v.z + v.w * v.w;
    ss += __shfl_xor(ss, 1);  ss += __shfl_xor(ss, 2);  ss += __shfl_xor(ss, 4);
    ss += __shfl_xor(ss, 8);  ss += __shfl_xor(ss, 16); ss += __shfl_xor(ss, 32);
    const float rr = rsqrtf(ss * (1.0f / LATq) + 1e-5f);
    const float4 g = *(const float4*)&wn[lane * 4];
    const unsigned w0 = pk2(v.x * rr * g.x, v.y * rr * g.y);
    const unsigned w1 = pk2(v.z * rr * g.z, v.w * rr * g.w);
    *(uint2*)&lat[(size_t)row * LATq + lane * 4] = make_uint2(w0, w1);
}

// ==== MFMA flash attention: 8 waves/block (unchanged from R10, 74 µs) =========
__global__ void __launch_bounds__(512)
mla_attn(const bf16* __restrict__ q, const bf16* __restrict__ kk,
         const bf16* __restrict__ vv, bf16* __restrict__ ao) {
    __shared__ __align__(16) short Ks[2][64 * 48];
    __shared__ __align__(16) short Vt[2][48 * 72];
    __shared__ __align__(16) short Ps[8][16 * 72];
    const int t    = threadIdx.x;
    const int g    = blockIdx.x;
    const int qy   = blockIdx.y;
    const int b    = blockIdx.z;
    const int qt0  = (qy < 16) ? (qy << 1) : (63 - (qy << 1));
    const int qt   = b ? (31 - qt0) : qt0;
    const int w    = t >> 6;                    // 0..7
    const int lane = t & 63;
    const int lr   = t & 15;
    const int quad = (t >> 4) & 3;
    const int hh   = w & 1;
    const int rh   = w >> 1;                    // 0..3: 16-row subtile
    const int h    = g * 2 + hh;
    const float scale = 0.14433756729740643f;   // 1/sqrt(48)
    const short8 z8 = {0, 0, 0, 0, 0, 0, 0, 0};

    // Q fragment (B-operand): lane holds Q[q = lr][d = ks*32 + quad*8 + j]
    const int qloc = rh * 16 + lr;              // row within the 64-row tile
    const int qg   = qt * 64 + qloc;            // global row
    const bf16* qr = q + (size_t)(b * Tq + qg) * QN + h * HDq;
    short8 qf0 = *(const short8*)(qr + quad * 8);
    const short8 q1 = *(const short8*)(qr + 32 + (quad & 1) * 8);
    short8 qf1 = (quad < 2) ? q1 : z8;

    const bf16* kb = kk + (size_t)b * Tq * KVN + g * HDq;
    const bf16* vb = vv + (size_t)b * Tq * KVN + g * HDq;

    float m = -1e30f, l = 0.f;
    f32x4 acc[3];
    #pragma unroll
    for (int dm = 0; dm < 3; ++dm) acc[dm] = (f32x4){0.f, 0.f, 0.f, 0.f};

    short* Pw = &Ps[w][0];
    uint4 pre[3];

    // staging roles: waves 0,1 -> K (384 uint4 tasks); waves 2,3 -> V^T;
    // waves 4-7 compute-only (wait at barrier while stagers write).
    auto issue = [&](int tl) {
        if (w >= 4) return;
        #pragma unroll
        for (int r = 0; r < 3; ++r) {
            if (w < 2) {
                const int idx = (w * 3 + r) * 64 + lane;
                const int row = idx / 6, ch = idx - row * 6;
                pre[r] = *(const uint4*)(kb + (size_t)(tl * 64 + row) * KVN + ch * 8);
            } else {
                const int idx = ((w - 2) * 3 + r) * 64 + lane;
                const int kp = idx & 31, hc = idx >> 5;
                const bf16* src = vb + (size_t)(tl * 64 + 2 * kp) * KVN + hc * 4;
                const uint2 a2 = *(const uint2*)src;
                const uint2 b2 = *(const uint2*)(src + KVN);
                pre[r].x = a2.x; pre[r].y = a2.y; pre[r].z = b2.x; pre[r].w = b2.y;
            }
        }
    };
    auto lwrite = [&](int bb) {
        if (w >= 4) return;
        #pragma unroll
        for (int r = 0; r < 3; ++r) {
            if (w < 2) {
                const int idx = (w * 3 + r) * 64 + lane;
                const int row = idx / 6, ch = idx - row * 6;
                *(uint4*)&Ks[bb][row * 48 + ch * 8] = pre[r];
            } else {
                const int idx = ((w - 2) * 3 + r) * 64 + lane;
                const int kp = idx & 31, hc = idx >> 5;
                const unsigned short* uu = (const unsigned short*)&pre[r];
                #pragma unroll
                for (int j = 0; j < 4; ++j)
                    *(unsigned*)&Vt[bb][(hc * 4 + j) * 72 + 2 * kp] =
                        (unsigned)uu[j] | ((unsigned)uu[4 + j] << 16);
            }
        }
    };

    issue(0);
    lwrite(0);
    __syncthreads();
    int cur = 0;

    for (int tl = 0; tl <= qt; ++tl) {
        const bool pref = (tl < qt);
        if (pref) issue(tl + 1);

        // S^T[key][q] = K·Q^T : lane holds key = mt*16 + quad*4 + r, q = lr
        f32x4 sc[4];
        #pragma unroll
        for (int mt = 0; mt < 4; ++mt) {
            const short8 k0 = *(const short8*)&Ks[cur][(mt * 16 + lr) * 48 + quad * 8];
            const short8 k1v = *(const short8*)&Ks[cur][(mt * 16 + lr) * 48 + 32 + (quad & 1) * 8];
            const short8 k1 = (quad < 2) ? k1v : z8;
            f32x4 s = (f32x4){0.f, 0.f, 0.f, 0.f};
            s = __builtin_amdgcn_mfma_f32_16x16x32_bf16(k0, qf0, s, 0, 0, 0);
            s = __builtin_amdgcn_mfma_f32_16x16x32_bf16(k1, qf1, s, 0, 0, 0);
            sc[mt] = s;
        }
        if (tl == qt) {                         // diagonal tile: mask key > q
            #pragma unroll
            for (int mt = 0; mt < 4; ++mt)
                #pragma unroll
                for (int r = 0; r < 4; ++r)
                    if (mt * 16 + quad * 4 + r > qloc) sc[mt][r] = -1e30f;
        }
        float mx = -1e30f;
        #pragma unroll
        for (int mt = 0; mt < 4; ++mt)
            #pragma unroll
            for (int r = 0; r < 4; ++r) mx = fmaxf(mx, sc[mt][r]);
        mx = fmaxf(mx, __shfl_xor(mx, 16));
        mx = fmaxf(mx, __shfl_xor(mx, 32));
        const float mn = fmaxf(m, mx * scale);
        const float f  = __expf(m - mn);
        m = mn;
        float rs = 0.f;
        #pragma unroll
        for (int mt = 0; mt < 4; ++mt)
            #pragma unroll
            for (int r = 0; r < 4; ++r) {
                const float p = u2f(f2u(__expf(fmaf(sc[mt][r], scale, -mn))));
                sc[mt][r] = p;                  // bf16-rounded weight
                rs += p;
            }
        rs += __shfl_xor(rs, 16);
        rs += __shfl_xor(rs, 32);
        l = l * f + rs;
        #pragma unroll
        for (int dm = 0; dm < 3; ++dm)
            #pragma unroll
            for (int r = 0; r < 4; ++r) acc[dm][r] *= f;
        // pack P to per-wave scratch: Pw[q=lr][key], key pairs -> u32
        #pragma unroll
        for (int mt = 0; mt < 4; ++mt) {
            unsigned* pw = (unsigned*)&Pw[lr * 72 + mt * 16 + quad * 4];
            pw[0] = pk2(sc[mt][0], sc[mt][1]);
            pw[1] = pk2(sc[mt][2], sc[mt][3]);
        }
        // B-frag read-back: lane holds P[q=lr][key = ks*32 + quad*8 + j]
        const short8 pf0 = *(const short8*)&Pw[lr * 72 + quad * 8];
        const short8 pf1 = *(const short8*)&Pw[lr * 72 + 32 + quad * 8];
        // O^T[d][q] += V^T·P^T : lane accumulates d = dm*16 + quad*4 + r, q = lr
        #pragma unroll
        for (int dm = 0; dm < 3; ++dm) {
            const short8 v0 = *(const short8*)&Vt[cur][(dm * 16 + lr) * 72 + quad * 8];
            const short8 v1 = *(const short8*)&Vt[cur][(dm * 16 + lr) * 72 + 32 + quad * 8];
            acc[dm] = __builtin_amdgcn_mfma_f32_16x16x32_bf16(v0, pf0, acc[dm], 0, 0, 0);
            acc[dm] = __builtin_amdgcn_mfma_f32_16x16x32_bf16(v1, pf1, acc[dm], 0, 0, 0);
        }

        if (pref) lwrite(cur ^ 1);              // overlapped with compute
        __syncthreads();
        cur ^= 1;
    }

    const float inv = 1.0f / l;
    bf16* orow = ao + (size_t)(b * Tq + qg) * QN + h * HDq;
    #pragma unroll
    for (int dm = 0; dm < 3; ++dm) {
        const unsigned w0 = pk2(acc[dm][0] * inv, acc[dm][1] * inv);
        const unsigned w1 = pk2(acc[dm][2] * inv, acc[dm][3] * inv);
        *(uint2*)(orow + dm * 16 + quad * 4) = make_uint2(w0, w1);
    }
}

extern "C" void kernel_launch(void* const* d_in, const int* in_sizes, int n_in,
                              void* d_out, int out_size, void* d_ws, size_t ws_size,
                              hipStream_t stream) {
    const float* x   = (const float*)d_in[0];
    // d_in[1]: causal mask — static tril, applied analytically in mla_attn
    const float* Wq  = (const float*)d_in[2];
    const float* Wkv = (const float*)d_in[3];
    const float* wn  = (const float*)d_in[4];
    const float* Wk  = (const float*)d_in[5];
    const float* Wv  = (const float*)d_in[6];
    const float* Wo  = (const float*)d_in[7];
    float* out = (float*)d_out;

    const int M = Bq * Tq;                          // 4096
    // d_out staging (all dead before oproj's final write; exactly 33,554,432 B):
    //   [0        : 16.78M)  xb     bf16 [4096 x 2048]  (dead after gemm_qkv)
    //   [16.78M   : 23.07M)  q      bf16 [4096 x 768]
    //   [23.07M   : 27.26M)  xkv    fp32 [4096 x 256]
    //   [27.26M   : 29.36M)  lat    bf16 [4096 x 256]
    //   [29.36M   : 33.55M)  WqkvT  bf16 [1024 x 2048]  (rows 0-767 Wq, 768+ Wkv)
    //   [WkT;WvT] bf16 [768 x 256] reuses xb region after gemm_qkv (stream-ord).
    char* ob = (char*)d_out;
    bf16*  xb    = (bf16*)ob;
    bf16*  qws   = (bf16*)(ob + 16777216);
    float* xkv   = (float*)(ob + 23068672);
    bf16*  latb  = (bf16*)(ob + 27262976);
    bf16*  WqkvT = (bf16*)(ob + 29360128);
    bf16*  WkvpT = (bf16*)ob;                       // after gemm_qkv
    // ws: k bf16 3.15M | v bf16 3.15M | ao bf16 6.29M; WoT reuses k after attn.
    bf16*  kws = (bf16*)d_ws;
    bf16*  vws = kws + (size_t)M * KVN;
    bf16*  aob = vws + (size_t)M * KVN;
    bf16*  WoT = (bf16*)d_ws;                       // after attn

    cvt_x <<<4096, 256, 0, stream>>>(x, xb);
    tr_w  <<<dim3(QN / 32, Dq / 32), 256, 0, stream>>>(Wq, WqkvT, Dq, QN);
    tr_w  <<<dim3(LATq / 32, Dq / 32), 256, 0, stream>>>(Wkv, WqkvT + (size_t)QN * Dq, Dq, LATq);
    gemm64<0> <<<dim3(M / 64, 1024 / 64), 256, 0, stream>>>(xb, WqkvT, qws, xkv, Dq);
    tr_w  <<<dim3(KVN / 32, LATq / 32), 256, 0, stream>>>(Wk, WkvpT, LATq, KVN);
    tr_w  <<<dim3(KVN / 32, LATq / 32), 256, 0, stream>>>(Wv, WkvpT + (size_t)KVN * LATq, LATq, KVN);
    mla_kvrms <<<M / 4, 256, 0, stream>>>(xkv, wn, latb);
    gemm64<1> <<<dim3(M / 64, 768 / 64), 256, 0, stream>>>(latb, WkvpT, kws, vws, LATq);
    mla_attn <<<dim3(NLHq, 32, Bq), 512, 0, stream>>>(qws, kws, vws, aob);
    tr_w  <<<dim3(Dq / 32, QN / 32), 256, 0, stream>>>(Wo, WoT, QN, Dq);
    gemm64<2> <<<dim3(M / 64, Dq / 64), 256, 0, stream>>>(aob, WoT, out, nullptr, QN);
}

// Round 12
// 263.670 us; speedup vs baseline: 1.0354x; 1.0354x over previous
//
#include <hip/hip_runtime.h>
#include <hip/hip_bf16.h>

typedef __hip_bfloat16 bf16;
typedef __attribute__((ext_vector_type(8))) short short8;
typedef __attribute__((ext_vector_type(4))) float f32x4;

#define Bq   2
#define Tq   2048
#define Dq   2048
#define NHq  16
#define HDq  48
#define LATq 256
#define NLHq 8
#define QN   (NHq * HDq)    // 768
#define KVN  (NLHq * HDq)   // 384

__device__ __forceinline__ unsigned short f2u(float x) {
    __hip_bfloat16 h = __float2bfloat16(x);
    return *reinterpret_cast<unsigned short*>(&h);
}
__device__ __forceinline__ float u2f(unsigned short u) {
    return __uint_as_float((unsigned)u << 16);
}
__device__ __forceinline__ unsigned pk2(float a, float b) {
    return (unsigned)f2u(a) | ((unsigned)f2u(b) << 16);
}

// ---- x fp32 -> bf16, 8 elems/thread ------------------------------------------
__global__ void __launch_bounds__(256)
cvt_x(const float* __restrict__ in, bf16* __restrict__ out) {
    const size_t i = ((size_t)blockIdx.x * 256 + threadIdx.x) * 8;
    const float4 a = *(const float4*)&in[i];
    const float4 b = *(const float4*)&in[i + 4];
    uint4 u;
    u.x = pk2(a.x, a.y); u.y = pk2(a.z, a.w);
    u.z = pk2(b.x, b.y); u.w = pk2(b.z, b.w);
    *(uint4*)&out[i] = u;
}

// ---- W fp32 [K][N] -> WT bf16 [N][K], 32x32 LDS tiles -------------------------
__global__ void __launch_bounds__(256)
tr_w(const float* __restrict__ W, bf16* __restrict__ WT, int K, int N) {
    __shared__ float ts[32][33];
    const int n0 = blockIdx.x * 32, k0 = blockIdx.y * 32;
    const int t = threadIdx.x;
    const int r = t >> 3, c4 = (t & 7) * 4;
    const float4 v = *(const float4*)&W[(size_t)(k0 + r) * N + n0 + c4];
    ts[r][c4] = v.x; ts[r][c4 + 1] = v.y; ts[r][c4 + 2] = v.z; ts[r][c4 + 3] = v.w;
    __syncthreads();
    const unsigned u0 = pk2(ts[c4][r], ts[c4 + 1][r]);
    const unsigned u1 = pk2(ts[c4 + 2][r], ts[c4 + 3][r]);
    *(uint2*)&WT[(size_t)(n0 + r) * K + k0 + c4] = make_uint2(u0, u1);
}

// ==== bf16 GEMM, 128x64 tile, 8 waves, double-buffered LDS ====================
// R11's 64x64 tile doubled total load traffic (A re-read 16x, BT 64x) and lost
// 19 us despite 4x blocks — tile shrink duplicates staging (same failure as
// attn-R9). This applies the attn R8->R10 fix to the GEMM instead: keep R8's
// 128x64 tile (traffic and LDS identical, FLOP/staged-byte 42.7) but split the
// block's work over 512 thr / 8 waves: wave w owns 32x32 (wm=(w&3)*32,
// wn=(w>>2)*32, 2x2 frags, 4 MFMA/k-step). Grids 512/384/1024 -> 16-32
// waves/CU (was 8) with byte-identical staging. Register-prefetch + one
// barrier per k-step (proven skeleton). A staged by all 512 thr (=512 uint4),
// B by thr<256. LDS 30.7KB; ~64 VGPR.
// Epilogue by MODE (64-col tiles never straddle the split points):
//   0: N=1024 fused qkv  -> col<768: q bf16 [.][768]; else xkv fp32 [.][256]
//   1: N=768  fused k|v  -> col<384: k bf16 [.][384]; else v bf16 [.][384]
//   2: N=2048 oproj      -> fp32 [.][2048]
template<int MODE>
__global__ void __launch_bounds__(512)
gemm128(const bf16* __restrict__ A, const bf16* __restrict__ BT,
        void* __restrict__ C0v, void* __restrict__ C1v, int K) {
    __shared__ short As[2][128 * 40];
    __shared__ short Bs[2][64 * 40];
    const int t  = threadIdx.x;
    const int m0 = blockIdx.x * 128;
    const int n0 = blockIdx.y * 64;
    const int w  = t >> 6;                      // 0..7
    const int wm = (w & 3) * 32;
    const int wn = (w >> 2) * 32;
    const int lr = t & 15;
    const int quad = (t >> 4) & 3;
    const int sr = t >> 2, sc = t & 3;          // staging row / 16B chunk

    f32x4 acc[2][2];
    #pragma unroll
    for (int mi = 0; mi < 2; ++mi)
        #pragma unroll
        for (int ni = 0; ni < 2; ++ni) acc[mi][ni] = (f32x4){0.f, 0.f, 0.f, 0.f};

    int aoff[2], boff[2];
    #pragma unroll
    for (int mi = 0; mi < 2; ++mi) aoff[mi] = (wm + mi * 16 + lr) * 40 + quad * 8;
    #pragma unroll
    for (int ni = 0; ni < 2; ++ni) boff[ni] = (wn + ni * 16 + lr) * 40 + quad * 8;

    uint4 pa0, pb0;
    auto glo = [&](int kt) {
        const int kb = kt * 32 + sc * 8;
        pa0 = *(const uint4*)&A[(size_t)(m0 + sr) * K + kb];      // sr in [0,128)
        if (t < 256) pb0 = *(const uint4*)&BT[(size_t)(n0 + sr) * K + kb];
    };
    auto lwrite = [&](int bb) {
        *(uint4*)&As[bb][sr * 40 + sc * 8] = pa0;
        if (t < 256) *(uint4*)&Bs[bb][sr * 40 + sc * 8] = pb0;
    };

    const int nk = K / 32;
    glo(0);
    lwrite(0);
    __syncthreads();
    int cur = 0;

    for (int kt = 0; kt < nk; ++kt) {
        const bool pref = (kt + 1 < nk);
        if (pref) glo(kt + 1);
        short8 af[2], bfr[2];
        #pragma unroll
        for (int mi = 0; mi < 2; ++mi) af[mi] = *(const short8*)&As[cur][aoff[mi]];
        #pragma unroll
        for (int ni = 0; ni < 2; ++ni) bfr[ni] = *(const short8*)&Bs[cur][boff[ni]];
        #pragma unroll
        for (int mi = 0; mi < 2; ++mi)
            #pragma unroll
            for (int ni = 0; ni < 2; ++ni)
                acc[mi][ni] = __builtin_amdgcn_mfma_f32_16x16x32_bf16(af[mi], bfr[ni], acc[mi][ni], 0, 0, 0);
        if (pref) lwrite(cur ^ 1);
        __syncthreads();
        cur ^= 1;
    }

    #pragma unroll
    for (int mi = 0; mi < 2; ++mi)
        #pragma unroll
        for (int ni = 0; ni < 2; ++ni) {
            const int col = n0 + wn + ni * 16 + lr;
            #pragma unroll
            for (int r = 0; r < 4; ++r) {
                const int row = m0 + wm + mi * 16 + quad * 4 + r;
                const float v = acc[mi][ni][r];
                if constexpr (MODE == 0) {
                    if (col < QN) ((bf16*)C0v)[(size_t)row * QN + col] = __float2bfloat16(v);
                    else ((float*)C1v)[(size_t)row * LATq + (col - QN)] = v;
                } else if constexpr (MODE == 1) {
                    if (col < KVN) ((bf16*)C0v)[(size_t)row * KVN + col] = __float2bfloat16(v);
                    else ((bf16*)C1v)[(size_t)row * KVN + (col - KVN)] = __float2bfloat16(v);
                } else {
                    ((float*)C0v)[(size_t)row * Dq + col] = v;
                }
            }
        }
}

// ---- lat = rmsnorm(xkv)*wn : [4096,256]fp32 -> bf16. 1 wave per row. ----------
__global__ void __launch_bounds__(256)
mla_kvrms(const float* __restrict__ xkv, const float* __restrict__ wn,
          bf16* __restrict__ lat) {
    const int t = threadIdx.x;
    const int row = blockIdx.x * 4 + (t >> 6);
    const int lane = t & 63;
    const float4 v = *(const float4*)&xkv[(size_t)row * LATq + lane * 4];
    float ss = v.x * v.x + v.y * v.y + v.z * v.z + v.w * v.w;
    ss += __shfl_xor(ss, 1);  ss += __shfl_xor(ss, 2);  ss += __shfl_xor(ss, 4);
    ss += __shfl_xor(ss, 8);  ss += __shfl_xor(ss, 16); ss += __shfl_xor(ss, 32);
    const float rr = rsqrtf(ss * (1.0f / LATq) + 1e-5f);
    const float4 g = *(const float4*)&wn[lane * 4];
    const unsigned w0 = pk2(v.x * rr * g.x, v.y * rr * g.y);
    const unsigned w1 = pk2(v.z * rr * g.z, v.w * rr * g.w);
    *(uint2*)&lat[(size_t)row * LATq + lane * 4] = make_uint2(w0, w1);
}

// ==== MFMA flash attention: 8 waves/block (unchanged from R10/R11, ~68 µs) ====
__global__ void __launch_bounds__(512)
mla_attn(const bf16* __restrict__ q, const bf16* __restrict__ kk,
         const bf16* __restrict__ vv, bf16* __restrict__ ao) {
    __shared__ __align__(16) short Ks[2][64 * 48];
    __shared__ __align__(16) short Vt[2][48 * 72];
    __shared__ __align__(16) short Ps[8][16 * 72];
    const int t    = threadIdx.x;
    const int g    = blockIdx.x;
    const int qy   = blockIdx.y;
    const int b    = blockIdx.z;
    const int qt0  = (qy < 16) ? (qy << 1) : (63 - (qy << 1));
    const int qt   = b ? (31 - qt0) : qt0;
    const int w    = t >> 6;                    // 0..7
    const int lane = t & 63;
    const int lr   = t & 15;
    const int quad = (t >> 4) & 3;
    const int hh   = w & 1;
    const int rh   = w >> 1;                    // 0..3: 16-row subtile
    const int h    = g * 2 + hh;
    const float scale = 0.14433756729740643f;   // 1/sqrt(48)
    const short8 z8 = {0, 0, 0, 0, 0, 0, 0, 0};

    // Q fragment (B-operand): lane holds Q[q = lr][d = ks*32 + quad*8 + j]
    const int qloc = rh * 16 + lr;              // row within the 64-row tile
    const int qg   = qt * 64 + qloc;            // global row
    const bf16* qr = q + (size_t)(b * Tq + qg) * QN + h * HDq;
    short8 qf0 = *(const short8*)(qr + quad * 8);
    const short8 q1 = *(const short8*)(qr + 32 + (quad & 1) * 8);
    short8 qf1 = (quad < 2) ? q1 : z8;

    const bf16* kb = kk + (size_t)b * Tq * KVN + g * HDq;
    const bf16* vb = vv + (size_t)b * Tq * KVN + g * HDq;

    float m = -1e30f, l = 0.f;
    f32x4 acc[3];
    #pragma unroll
    for (int dm = 0; dm < 3; ++dm) acc[dm] = (f32x4){0.f, 0.f, 0.f, 0.f};

    short* Pw = &Ps[w][0];
    uint4 pre[3];

    // staging roles: waves 0,1 -> K (384 uint4 tasks); waves 2,3 -> V^T;
    // waves 4-7 compute-only (wait at barrier while stagers write).
    auto issue = [&](int tl) {
        if (w >= 4) return;
        #pragma unroll
        for (int r = 0; r < 3; ++r) {
            if (w < 2) {
                const int idx = (w * 3 + r) * 64 + lane;
                const int row = idx / 6, ch = idx - row * 6;
                pre[r] = *(const uint4*)(kb + (size_t)(tl * 64 + row) * KVN + ch * 8);
            } else {
                const int idx = ((w - 2) * 3 + r) * 64 + lane;
                const int kp = idx & 31, hc = idx >> 5;
                const bf16* src = vb + (size_t)(tl * 64 + 2 * kp) * KVN + hc * 4;
                const uint2 a2 = *(const uint2*)src;
                const uint2 b2 = *(const uint2*)(src + KVN);
                pre[r].x = a2.x; pre[r].y = a2.y; pre[r].z = b2.x; pre[r].w = b2.y;
            }
        }
    };
    auto lwrite = [&](int bb) {
        if (w >= 4) return;
        #pragma unroll
        for (int r = 0; r < 3; ++r) {
            if (w < 2) {
                const int idx = (w * 3 + r) * 64 + lane;
                const int row = idx / 6, ch = idx - row * 6;
                *(uint4*)&Ks[bb][row * 48 + ch * 8] = pre[r];
            } else {
                const int idx = ((w - 2) * 3 + r) * 64 + lane;
                const int kp = idx & 31, hc = idx >> 5;
                const unsigned short* uu = (const unsigned short*)&pre[r];
                #pragma unroll
                for (int j = 0; j < 4; ++j)
                    *(unsigned*)&Vt[bb][(hc * 4 + j) * 72 + 2 * kp] =
                        (unsigned)uu[j] | ((unsigned)uu[4 + j] << 16);
            }
        }
    };

    issue(0);
    lwrite(0);
    __syncthreads();
    int cur = 0;

    for (int tl = 0; tl <= qt; ++tl) {
        const bool pref = (tl < qt);
        if (pref) issue(tl + 1);

        // S^T[key][q] = K·Q^T : lane holds key = mt*16 + quad*4 + r, q = lr
        f32x4 sc[4];
        #pragma unroll
        for (int mt = 0; mt < 4; ++mt) {
            const short8 k0 = *(const short8*)&Ks[cur][(mt * 16 + lr) * 48 + quad * 8];
            const short8 k1v = *(const short8*)&Ks[cur][(mt * 16 + lr) * 48 + 32 + (quad & 1) * 8];
            const short8 k1 = (quad < 2) ? k1v : z8;
            f32x4 s = (f32x4){0.f, 0.f, 0.f, 0.f};
            s = __builtin_amdgcn_mfma_f32_16x16x32_bf16(k0, qf0, s, 0, 0, 0);
            s = __builtin_amdgcn_mfma_f32_16x16x32_bf16(k1, qf1, s, 0, 0, 0);
            sc[mt] = s;
        }
        if (tl == qt) {                         // diagonal tile: mask key > q
            #pragma unroll
            for (int mt = 0; mt < 4; ++mt)
                #pragma unroll
                for (int r = 0; r < 4; ++r)
                    if (mt * 16 + quad * 4 + r > qloc) sc[mt][r] = -1e30f;
        }
        float mx = -1e30f;
        #pragma unroll
        for (int mt = 0; mt < 4; ++mt)
            #pragma unroll
            for (int r = 0; r < 4; ++r) mx = fmaxf(mx, sc[mt][r]);
        mx = fmaxf(mx, __shfl_xor(mx, 16));
        mx = fmaxf(mx, __shfl_xor(mx, 32));
        const float mn = fmaxf(m, mx * scale);
        const float f  = __expf(m - mn);
        m = mn;
        float rs = 0.f;
        #pragma unroll
        for (int mt = 0; mt < 4; ++mt)
            #pragma unroll
            for (int r = 0; r < 4; ++r) {
                const float p = u2f(f2u(__expf(fmaf(sc[mt][r], scale, -mn))));
                sc[mt][r] = p;                  // bf16-rounded weight
                rs += p;
            }
        rs += __shfl_xor(rs, 16);
        rs += __shfl_xor(rs, 32);
        l = l * f + rs;
        #pragma unroll
        for (int dm = 0; dm < 3; ++dm)
            #pragma unroll
            for (int r = 0; r < 4; ++r) acc[dm][r] *= f;
        // pack P to per-wave scratch: Pw[q=lr][key], key pairs -> u32
        #pragma unroll
        for (int mt = 0; mt < 4; ++mt) {
            unsigned* pw = (unsigned*)&Pw[lr * 72 + mt * 16 + quad * 4];
            pw[0] = pk2(sc[mt][0], sc[mt][1]);
            pw[1] = pk2(sc[mt][2], sc[mt][3]);
        }
        // B-frag read-back: lane holds P[q=lr][key = ks*32 + quad*8 + j]
        const short8 pf0 = *(const short8*)&Pw[lr * 72 + quad * 8];
        const short8 pf1 = *(const short8*)&Pw[lr * 72 + 32 + quad * 8];
        // O^T[d][q] += V^T·P^T : lane accumulates d = dm*16 + quad*4 + r, q = lr
        #pragma unroll
        for (int dm = 0; dm < 3; ++dm) {
            const short8 v0 = *(const short8*)&Vt[cur][(dm * 16 + lr) * 72 + quad * 8];
            const short8 v1 = *(const short8*)&Vt[cur][(dm * 16 + lr) * 72 + 32 + quad * 8];
            acc[dm] = __builtin_amdgcn_mfma_f32_16x16x32_bf16(v0, pf0, acc[dm], 0, 0, 0);
            acc[dm] = __builtin_amdgcn_mfma_f32_16x16x32_bf16(v1, pf1, acc[dm], 0, 0, 0);
        }

        if (pref) lwrite(cur ^ 1);              // overlapped with compute
        __syncthreads();
        cur ^= 1;
    }

    const float inv = 1.0f / l;
    bf16* orow = ao + (size_t)(b * Tq + qg) * QN + h * HDq;
    #pragma unroll
    for (int dm = 0; dm < 3; ++dm) {
        const unsigned w0 = pk2(acc[dm][0] * inv, acc[dm][1] * inv);
        const unsigned w1 = pk2(acc[dm][2] * inv, acc[dm][3] * inv);
        *(uint2*)(orow + dm * 16 + quad * 4) = make_uint2(w0, w1);
    }
}

extern "C" void kernel_launch(void* const* d_in, const int* in_sizes, int n_in,
                              void* d_out, int out_size, void* d_ws, size_t ws_size,
                              hipStream_t stream) {
    const float* x   = (const float*)d_in[0];
    // d_in[1]: causal mask — static tril, applied analytically in mla_attn
    const float* Wq  = (const float*)d_in[2];
    const float* Wkv = (const float*)d_in[3];
    const float* wn  = (const float*)d_in[4];
    const float* Wk  = (const float*)d_in[5];
    const float* Wv  = (const float*)d_in[6];
    const float* Wo  = (const float*)d_in[7];
    float* out = (float*)d_out;

    const int M = Bq * Tq;                          // 4096
    // d_out staging (all dead before oproj's final write; exactly 33,554,432 B):
    //   [0        : 16.78M)  xb     bf16 [4096 x 2048]  (dead after gemm_qkv)
    //   [16.78M   : 23.07M)  q      bf16 [4096 x 768]
    //   [23.07M   : 27.26M)  xkv    fp32 [4096 x 256]
    //   [27.26M   : 29.36M)  lat    bf16 [4096 x 256]
    //   [29.36M   : 33.55M)  WqkvT  bf16 [1024 x 2048]  (rows 0-767 Wq, 768+ Wkv)
    //   [WkT;WvT] bf16 [768 x 256] reuses xb region after gemm_qkv (stream-ord).
    char* ob = (char*)d_out;
    bf16*  xb    = (bf16*)ob;
    bf16*  qws   = (bf16*)(ob + 16777216);
    float* xkv   = (float*)(ob + 23068672);
    bf16*  latb  = (bf16*)(ob + 27262976);
    bf16*  WqkvT = (bf16*)(ob + 29360128);
    bf16*  WkvpT = (bf16*)ob;                       // after gemm_qkv
    // ws: k bf16 3.15M | v bf16 3.15M | ao bf16 6.29M; WoT reuses k after attn.
    bf16*  kws = (bf16*)d_ws;
    bf16*  vws = kws + (size_t)M * KVN;
    bf16*  aob = vws + (size_t)M * KVN;
    bf16*  WoT = (bf16*)d_ws;                       // after attn

    cvt_x <<<4096, 256, 0, stream>>>(x, xb);
    tr_w  <<<dim3(QN / 32, Dq / 32), 256, 0, stream>>>(Wq, WqkvT, Dq, QN);
    tr_w  <<<dim3(LATq / 32, Dq / 32), 256, 0, stream>>>(Wkv, WqkvT + (size_t)QN * Dq, Dq, LATq);
    gemm128<0> <<<dim3(M / 128, 1024 / 64), 512, 0, stream>>>(xb, WqkvT, qws, xkv, Dq);
    tr_w  <<<dim3(KVN / 32, LATq / 32), 256, 0, stream>>>(Wk, WkvpT, LATq, KVN);
    tr_w  <<<dim3(KVN / 32, LATq / 32), 256, 0, stream>>>(Wv, WkvpT + (size_t)KVN * LATq, LATq, KVN);
    mla_kvrms <<<M / 4, 256, 0, stream>>>(xkv, wn, latb);
    gemm128<1> <<<dim3(M / 128, 768 / 64), 512, 0, stream>>>(latb, WkvpT, kws, vws, LATq);
    mla_attn <<<dim3(NLHq, 32, Bq), 512, 0, stream>>>(qws, kws, vws, aob);
    tr_w  <<<dim3(Dq / 32, QN / 32), 256, 0, stream>>>(Wo, WoT, QN, Dq);
    gemm128<2> <<<dim3(M / 128, Dq / 64), 512, 0, stream>>>(aob, WoT, out, nullptr, QN);
}

// Round 13
// 262.774 us; speedup vs baseline: 1.0389x; 1.0034x over previous
//
#include <hip/hip_runtime.h>
#include <hip/hip_bf16.h>

typedef __hip_bfloat16 bf16;
typedef __attribute__((ext_vector_type(8))) short short8;
typedef __attribute__((ext_vector_type(4))) float f32x4;

#define Bq   2
#define Tq   2048
#define Dq   2048
#define NHq  16
#define HDq  48
#define LATq 256
#define NLHq 8
#define QN   (NHq * HDq)    // 768
#define KVN  (NLHq * HDq)   // 384

__device__ __forceinline__ unsigned short f2u(float x) {
    __hip_bfloat16 h = __float2bfloat16(x);
    return *reinterpret_cast<unsigned short*>(&h);
}
__device__ __forceinline__ float u2f(unsigned short u) {
    return __uint_as_float((unsigned)u << 16);
}
__device__ __forceinline__ unsigned pk2(float a, float b) {
    return (unsigned)f2u(a) | ((unsigned)f2u(b) << 16);
}

// ---- x fp32 -> bf16, 8 elems/thread ------------------------------------------
__global__ void __launch_bounds__(256)
cvt_x(const float* __restrict__ in, bf16* __restrict__ out) {
    const size_t i = ((size_t)blockIdx.x * 256 + threadIdx.x) * 8;
    const float4 a = *(const float4*)&in[i];
    const float4 b = *(const float4*)&in[i + 4];
    uint4 u;
    u.x = pk2(a.x, a.y); u.y = pk2(a.z, a.w);
    u.z = pk2(b.x, b.y); u.w = pk2(b.z, b.w);
    *(uint4*)&out[i] = u;
}

// ---- W fp32 [K][N] -> WT bf16 [N][K], 32x32 LDS tiles -------------------------
__global__ void __launch_bounds__(256)
tr_w(const float* __restrict__ W, bf16* __restrict__ WT, int K, int N) {
    __shared__ float ts[32][33];
    const int n0 = blockIdx.x * 32, k0 = blockIdx.y * 32;
    const int t = threadIdx.x;
    const int r = t >> 3, c4 = (t & 7) * 4;
    const float4 v = *(const float4*)&W[(size_t)(k0 + r) * N + n0 + c4];
    ts[r][c4] = v.x; ts[r][c4 + 1] = v.y; ts[r][c4 + 2] = v.z; ts[r][c4 + 3] = v.w;
    __syncthreads();
    const unsigned u0 = pk2(ts[c4][r], ts[c4 + 1][r]);
    const unsigned u1 = pk2(ts[c4 + 2][r], ts[c4 + 3][r]);
    *(uint2*)&WT[(size_t)(n0 + r) * K + k0 + c4] = make_uint2(u0, u1);
}

// ==== bf16 GEMM, 128x64 tile, 8 waves, DEEP-PIPELINED (T14) ===================
// R8/R10/R12 all had: glo(kt+1) at top, lwrite (vmcnt wait) at bottom of the
// SAME iteration -> only the ~30cyc MFMA block hid under ~400cyc load latency;
// every k-step paid nearly full latency (GEMMs stuck ~230 TF regardless of
// wave split). Now loads are issued TWO iterations ahead:
//   compute(LDS[cur]); lwrite(LDS[cur^1]) <- pre (kt+1, issued last iter:
//   vmcnt already satisfied); glo(pre <- kt+2) [stays in flight ACROSS the
//   barrier - T14 pattern, register loads aren't drained by __syncthreads];
//   barrier.
// Per-iter critical path: max(MFMA+ds_write, barrier) instead of load latency.
// WAR on pre safe (lwrite reads before glo overwrites); LDS[cur^1] consumed
// one iter ago behind a barrier. Geometry unchanged: 512 thr / 8 waves, wave
// owns 32x32 (2x2 frags), A staged by 512 thr, B by thr<256; LDS 30.7KB.
// Epilogue by MODE (64-col tiles never straddle the split points):
//   0: N=1024 fused qkv  -> col<768: q bf16 [.][768]; else xkv fp32 [.][256]
//   1: N=768  fused k|v  -> col<384: k bf16 [.][384]; else v bf16 [.][384]
//   2: N=2048 oproj      -> fp32 [.][2048]
template<int MODE>
__global__ void __launch_bounds__(512)
gemm128(const bf16* __restrict__ A, const bf16* __restrict__ BT,
        void* __restrict__ C0v, void* __restrict__ C1v, int K) {
    __shared__ short As[2][128 * 40];
    __shared__ short Bs[2][64 * 40];
    const int t  = threadIdx.x;
    const int m0 = blockIdx.x * 128;
    const int n0 = blockIdx.y * 64;
    const int w  = t >> 6;                      // 0..7
    const int wm = (w & 3) * 32;
    const int wn = (w >> 2) * 32;
    const int lr = t & 15;
    const int quad = (t >> 4) & 3;
    const int sr = t >> 2, sc = t & 3;          // staging row / 16B chunk

    f32x4 acc[2][2];
    #pragma unroll
    for (int mi = 0; mi < 2; ++mi)
        #pragma unroll
        for (int ni = 0; ni < 2; ++ni) acc[mi][ni] = (f32x4){0.f, 0.f, 0.f, 0.f};

    int aoff[2], boff[2];
    #pragma unroll
    for (int mi = 0; mi < 2; ++mi) aoff[mi] = (wm + mi * 16 + lr) * 40 + quad * 8;
    #pragma unroll
    for (int ni = 0; ni < 2; ++ni) boff[ni] = (wn + ni * 16 + lr) * 40 + quad * 8;

    uint4 pa0, pb0;
    auto glo = [&](int kt) {
        const int kb = kt * 32 + sc * 8;
        pa0 = *(const uint4*)&A[(size_t)(m0 + sr) * K + kb];      // sr in [0,128)
        if (t < 256) pb0 = *(const uint4*)&BT[(size_t)(n0 + sr) * K + kb];
    };
    auto lwrite = [&](int bb) {
        *(uint4*)&As[bb][sr * 40 + sc * 8] = pa0;
        if (t < 256) *(uint4*)&Bs[bb][sr * 40 + sc * 8] = pb0;
    };

    const int nk = K / 32;
    glo(0);
    lwrite(0);
    glo(1);                                     // k1 in flight across barrier
    __syncthreads();
    int cur = 0;

    for (int kt = 0; kt < nk; ++kt) {
        short8 af[2], bfr[2];
        #pragma unroll
        for (int mi = 0; mi < 2; ++mi) af[mi] = *(const short8*)&As[cur][aoff[mi]];
        #pragma unroll
        for (int ni = 0; ni < 2; ++ni) bfr[ni] = *(const short8*)&Bs[cur][boff[ni]];
        #pragma unroll
        for (int mi = 0; mi < 2; ++mi)
            #pragma unroll
            for (int ni = 0; ni < 2; ++ni)
                acc[mi][ni] = __builtin_amdgcn_mfma_f32_16x16x32_bf16(af[mi], bfr[ni], acc[mi][ni], 0, 0, 0);
        if (kt + 1 < nk) lwrite(cur ^ 1);       // kt+1 data: issued last iter
        if (kt + 2 < nk) glo(kt + 2);           // stays in flight across barrier
        __syncthreads();
        cur ^= 1;
    }

    #pragma unroll
    for (int mi = 0; mi < 2; ++mi)
        #pragma unroll
        for (int ni = 0; ni < 2; ++ni) {
            const int col = n0 + wn + ni * 16 + lr;
            #pragma unroll
            for (int r = 0; r < 4; ++r) {
                const int row = m0 + wm + mi * 16 + quad * 4 + r;
                const float v = acc[mi][ni][r];
                if constexpr (MODE == 0) {
                    if (col < QN) ((bf16*)C0v)[(size_t)row * QN + col] = __float2bfloat16(v);
                    else ((float*)C1v)[(size_t)row * LATq + (col - QN)] = v;
                } else if constexpr (MODE == 1) {
                    if (col < KVN) ((bf16*)C0v)[(size_t)row * KVN + col] = __float2bfloat16(v);
                    else ((bf16*)C1v)[(size_t)row * KVN + (col - KVN)] = __float2bfloat16(v);
                } else {
                    ((float*)C0v)[(size_t)row * Dq + col] = v;
                }
            }
        }
}

// ---- lat = rmsnorm(xkv)*wn : [4096,256]fp32 -> bf16. 1 wave per row. ----------
__global__ void __launch_bounds__(256)
mla_kvrms(const float* __restrict__ xkv, const float* __restrict__ wn,
          bf16* __restrict__ lat) {
    const int t = threadIdx.x;
    const int row = blockIdx.x * 4 + (t >> 6);
    const int lane = t & 63;
    const float4 v = *(const float4*)&xkv[(size_t)row * LATq + lane * 4];
    float ss = v.x * v.x + v.y * v.y + v.z * v.z + v.w * v.w;
    ss += __shfl_xor(ss, 1);  ss += __shfl_xor(ss, 2);  ss += __shfl_xor(ss, 4);
    ss += __shfl_xor(ss, 8);  ss += __shfl_xor(ss, 16); ss += __shfl_xor(ss, 32);
    const float rr = rsqrtf(ss * (1.0f / LATq) + 1e-5f);
    const float4 g = *(const float4*)&wn[lane * 4];
    const unsigned w0 = pk2(v.x * rr * g.x, v.y * rr * g.y);
    const unsigned w1 = pk2(v.z * rr * g.z, v.w * rr * g.w);
    *(uint2*)&lat[(size_t)row * LATq + lane * 4] = make_uint2(w0, w1);
}

// ==== MFMA flash attention: 8 waves/block (unchanged, ~68-74 µs) ==============
__global__ void __launch_bounds__(512)
mla_attn(const bf16* __restrict__ q, const bf16* __restrict__ kk,
         const bf16* __restrict__ vv, bf16* __restrict__ ao) {
    __shared__ __align__(16) short Ks[2][64 * 48];
    __shared__ __align__(16) short Vt[2][48 * 72];
    __shared__ __align__(16) short Ps[8][16 * 72];
    const int t    = threadIdx.x;
    const int g    = blockIdx.x;
    const int qy   = blockIdx.y;
    const int b    = blockIdx.z;
    const int qt0  = (qy < 16) ? (qy << 1) : (63 - (qy << 1));
    const int qt   = b ? (31 - qt0) : qt0;
    const int w    = t >> 6;                    // 0..7
    const int lane = t & 63;
    const int lr   = t & 15;
    const int quad = (t >> 4) & 3;
    const int hh   = w & 1;
    const int rh   = w >> 1;                    // 0..3: 16-row subtile
    const int h    = g * 2 + hh;
    const float scale = 0.14433756729740643f;   // 1/sqrt(48)
    const short8 z8 = {0, 0, 0, 0, 0, 0, 0, 0};

    // Q fragment (B-operand): lane holds Q[q = lr][d = ks*32 + quad*8 + j]
    const int qloc = rh * 16 + lr;              // row within the 64-row tile
    const int qg   = qt * 64 + qloc;            // global row
    const bf16* qr = q + (size_t)(b * Tq + qg) * QN + h * HDq;
    short8 qf0 = *(const short8*)(qr + quad * 8);
    const short8 q1 = *(const short8*)(qr + 32 + (quad & 1) * 8);
    short8 qf1 = (quad < 2) ? q1 : z8;

    const bf16* kb = kk + (size_t)b * Tq * KVN + g * HDq;
    const bf16* vb = vv + (size_t)b * Tq * KVN + g * HDq;

    float m = -1e30f, l = 0.f;
    f32x4 acc[3];
    #pragma unroll
    for (int dm = 0; dm < 3; ++dm) acc[dm] = (f32x4){0.f, 0.f, 0.f, 0.f};

    short* Pw = &Ps[w][0];
    uint4 pre[3];

    // staging roles: waves 0,1 -> K (384 uint4 tasks); waves 2,3 -> V^T;
    // waves 4-7 compute-only (wait at barrier while stagers write).
    auto issue = [&](int tl) {
        if (w >= 4) return;
        #pragma unroll
        for (int r = 0; r < 3; ++r) {
            if (w < 2) {
                const int idx = (w * 3 + r) * 64 + lane;
                const int row = idx / 6, ch = idx - row * 6;
                pre[r] = *(const uint4*)(kb + (size_t)(tl * 64 + row) * KVN + ch * 8);
            } else {
                const int idx = ((w - 2) * 3 + r) * 64 + lane;
                const int kp = idx & 31, hc = idx >> 5;
                const bf16* src = vb + (size_t)(tl * 64 + 2 * kp) * KVN + hc * 4;
                const uint2 a2 = *(const uint2*)src;
                const uint2 b2 = *(const uint2*)(src + KVN);
                pre[r].x = a2.x; pre[r].y = a2.y; pre[r].z = b2.x; pre[r].w = b2.y;
            }
        }
    };
    auto lwrite = [&](int bb) {
        if (w >= 4) return;
        #pragma unroll
        for (int r = 0; r < 3; ++r) {
            if (w < 2) {
                const int idx = (w * 3 + r) * 64 + lane;
                const int row = idx / 6, ch = idx - row * 6;
                *(uint4*)&Ks[bb][row * 48 + ch * 8] = pre[r];
            } else {
                const int idx = ((w - 2) * 3 + r) * 64 + lane;
                const int kp = idx & 31, hc = idx >> 5;
                const unsigned short* uu = (const unsigned short*)&pre[r];
                #pragma unroll
                for (int j = 0; j < 4; ++j)
                    *(unsigned*)&Vt[bb][(hc * 4 + j) * 72 + 2 * kp] =
                        (unsigned)uu[j] | ((unsigned)uu[4 + j] << 16);
            }
        }
    };

    issue(0);
    lwrite(0);
    __syncthreads();
    int cur = 0;

    for (int tl = 0; tl <= qt; ++tl) {
        const bool pref = (tl < qt);
        if (pref) issue(tl + 1);

        // S^T[key][q] = K·Q^T : lane holds key = mt*16 + quad*4 + r, q = lr
        f32x4 sc[4];
        #pragma unroll
        for (int mt = 0; mt < 4; ++mt) {
            const short8 k0 = *(const short8*)&Ks[cur][(mt * 16 + lr) * 48 + quad * 8];
            const short8 k1v = *(const short8*)&Ks[cur][(mt * 16 + lr) * 48 + 32 + (quad & 1) * 8];
            const short8 k1 = (quad < 2) ? k1v : z8;
            f32x4 s = (f32x4){0.f, 0.f, 0.f, 0.f};
            s = __builtin_amdgcn_mfma_f32_16x16x32_bf16(k0, qf0, s, 0, 0, 0);
            s = __builtin_amdgcn_mfma_f32_16x16x32_bf16(k1, qf1, s, 0, 0, 0);
            sc[mt] = s;
        }
        if (tl == qt) {                         // diagonal tile: mask key > q
            #pragma unroll
            for (int mt = 0; mt < 4; ++mt)
                #pragma unroll
                for (int r = 0; r < 4; ++r)
                    if (mt * 16 + quad * 4 + r > qloc) sc[mt][r] = -1e30f;
        }
        float mx = -1e30f;
        #pragma unroll
        for (int mt = 0; mt < 4; ++mt)
            #pragma unroll
            for (int r = 0; r < 4; ++r) mx = fmaxf(mx, sc[mt][r]);
        mx = fmaxf(mx, __shfl_xor(mx, 16));
        mx = fmaxf(mx, __shfl_xor(mx, 32));
        const float mn = fmaxf(m, mx * scale);
        const float f  = __expf(m - mn);
        m = mn;
        float rs = 0.f;
        #pragma unroll
        for (int mt = 0; mt < 4; ++mt)
            #pragma unroll
            for (int r = 0; r < 4; ++r) {
                const float p = u2f(f2u(__expf(fmaf(sc[mt][r], scale, -mn))));
                sc[mt][r] = p;                  // bf16-rounded weight
                rs += p;
            }
        rs += __shfl_xor(rs, 16);
        rs += __shfl_xor(rs, 32);
        l = l * f + rs;
        #pragma unroll
        for (int dm = 0; dm < 3; ++dm)
            #pragma unroll
            for (int r = 0; r < 4; ++r) acc[dm][r] *= f;
        // pack P to per-wave scratch: Pw[q=lr][key], key pairs -> u32
        #pragma unroll
        for (int mt = 0; mt < 4; ++mt) {
            unsigned* pw = (unsigned*)&Pw[lr * 72 + mt * 16 + quad * 4];
            pw[0] = pk2(sc[mt][0], sc[mt][1]);
            pw[1] = pk2(sc[mt][2], sc[mt][3]);
        }
        // B-frag read-back: lane holds P[q=lr][key = ks*32 + quad*8 + j]
        const short8 pf0 = *(const short8*)&Pw[lr * 72 + quad * 8];
        const short8 pf1 = *(const short8*)&Pw[lr * 72 + 32 + quad * 8];
        // O^T[d][q] += V^T·P^T : lane accumulates d = dm*16 + quad*4 + r, q = lr
        #pragma unroll
        for (int dm = 0; dm < 3; ++dm) {
            const short8 v0 = *(const short8*)&Vt[cur][(dm * 16 + lr) * 72 + quad * 8];
            const short8 v1 = *(const short8*)&Vt[cur][(dm * 16 + lr) * 72 + 32 + quad * 8];
            acc[dm] = __builtin_amdgcn_mfma_f32_16x16x32_bf16(v0, pf0, acc[dm], 0, 0, 0);
            acc[dm] = __builtin_amdgcn_mfma_f32_16x16x32_bf16(v1, pf1, acc[dm], 0, 0, 0);
        }

        if (pref) lwrite(cur ^ 1);              // overlapped with compute
        __syncthreads();
        cur ^= 1;
    }

    const float inv = 1.0f / l;
    bf16* orow = ao + (size_t)(b * Tq + qg) * QN + h * HDq;
    #pragma unroll
    for (int dm = 0; dm < 3; ++dm) {
        const unsigned w0 = pk2(acc[dm][0] * inv, acc[dm][1] * inv);
        const unsigned w1 = pk2(acc[dm][2] * inv, acc[dm][3] * inv);
        *(uint2*)(orow + dm * 16 + quad * 4) = make_uint2(w0, w1);
    }
}

extern "C" void kernel_launch(void* const* d_in, const int* in_sizes, int n_in,
                              void* d_out, int out_size, void* d_ws, size_t ws_size,
                              hipStream_t stream) {
    const float* x   = (const float*)d_in[0];
    // d_in[1]: causal mask — static tril, applied analytically in mla_attn
    const float* Wq  = (const float*)d_in[2];
    const float* Wkv = (const float*)d_in[3];
    const float* wn  = (const float*)d_in[4];
    const float* Wk  = (const float*)d_in[5];
    const float* Wv  = (const float*)d_in[6];
    const float* Wo  = (const float*)d_in[7];
    float* out = (float*)d_out;

    const int M = Bq * Tq;                          // 4096
    // d_out staging (all dead before oproj's final write; exactly 33,554,432 B):
    //   [0        : 16.78M)  xb     bf16 [4096 x 2048]  (dead after gemm_qkv)
    //   [16.78M   : 23.07M)  q      bf16 [4096 x 768]
    //   [23.07M   : 27.26M)  xkv    fp32 [4096 x 256]
    //   [27.26M   : 29.36M)  lat    bf16 [4096 x 256]
    //   [29.36M   : 33.55M)  WqkvT  bf16 [1024 x 2048]  (rows 0-767 Wq, 768+ Wkv)
    //   [WkT;WvT] bf16 [768 x 256] reuses xb region after gemm_qkv (stream-ord).
    char* ob = (char*)d_out;
    bf16*  xb    = (bf16*)ob;
    bf16*  qws   = (bf16*)(ob + 16777216);
    float* xkv   = (float*)(ob + 23068672);
    bf16*  latb  = (bf16*)(ob + 27262976);
    bf16*  WqkvT = (bf16*)(ob + 29360128);
    bf16*  WkvpT = (bf16*)ob;                       // after gemm_qkv
    // ws: k bf16 3.15M | v bf16 3.15M | ao bf16 6.29M; WoT reuses k after attn.
    bf16*  kws = (bf16*)d_ws;
    bf16*  vws = kws + (size_t)M * KVN;
    bf16*  aob = vws + (size_t)M * KVN;
    bf16*  WoT = (bf16*)d_ws;                       // after attn

    cvt_x <<<4096, 256, 0, stream>>>(x, xb);
    tr_w  <<<dim3(QN / 32, Dq / 32), 256, 0, stream>>>(Wq, WqkvT, Dq, QN);
    tr_w  <<<dim3(LATq / 32, Dq / 32), 256, 0, stream>>>(Wkv, WqkvT + (size_t)QN * Dq, Dq, LATq);
    gemm128<0> <<<dim3(M / 128, 1024 / 64), 512, 0, stream>>>(xb, WqkvT, qws, xkv, Dq);
    tr_w  <<<dim3(KVN / 32, LATq / 32), 256, 0, stream>>>(Wk, WkvpT, LATq, KVN);
    tr_w  <<<dim3(KVN / 32, LATq / 32), 256, 0, stream>>>(Wv, WkvpT + (size_t)KVN * LATq, LATq, KVN);
    mla_kvrms <<<M / 4, 256, 0, stream>>>(xkv, wn, latb);
    gemm128<1> <<<dim3(M / 128, 768 / 64), 512, 0, stream>>>(latb, WkvpT, kws, vws, LATq);
    mla_attn <<<dim3(NLHq, 32, Bq), 512, 0, stream>>>(qws, kws, vws, aob);
    tr_w  <<<dim3(Dq / 32, QN / 32), 256, 0, stream>>>(Wo, WoT, QN, Dq);
    gemm128<2> <<<dim3(M / 128, Dq / 64), 512, 0, stream>>>(aob, WoT, out, nullptr, QN);
}

// Round 15
// 258.568 us; speedup vs baseline: 1.0558x; 1.0163x over previous
//
#include <hip/hip_runtime.h>
#include <hip/hip_bf16.h>

typedef __hip_bfloat16 bf16;
typedef __attribute__((ext_vector_type(8))) short short8;
typedef __attribute__((ext_vector_type(4))) float f32x4;

#define Bq   2
#define Tq   2048
#define Dq   2048
#define NHq  16
#define HDq  48
#define LATq 256
#define NLHq 8
#define QN   (NHq * HDq)    // 768
#define KVN  (NLHq * HDq)   // 384

__device__ __forceinline__ unsigned short f2u(float x) {
    __hip_bfloat16 h = __float2bfloat16(x);
    return *reinterpret_cast<unsigned short*>(&h);
}
__device__ __forceinline__ float u2f(unsigned short u) {
    return __uint_as_float((unsigned)u << 16);
}
__device__ __forceinline__ unsigned pk2(float a, float b) {
    return (unsigned)f2u(a) | ((unsigned)f2u(b) << 16);
}

// Non-draining barrier: __syncthreads() compiles to s_waitcnt vmcnt(0)
// lgkmcnt(0) + s_barrier — the vmcnt(0) drain killed every GEMM pipeline
// attempt (R12/R13 nulls). This waits lgkm only (LDS writes visible); global
// loads stay in flight across the barrier (guide's verified m201 pattern:
// raw s_barrier is NOT auto-drained). "memory" pins compile-time ordering.
__device__ __forceinline__ void lds_barrier() {
    asm volatile("s_waitcnt lgkmcnt(0)" ::: "memory");
    __builtin_amdgcn_s_barrier();
    asm volatile("" ::: "memory");
}

// ---- weight transpose tile body: W fp32 [K][N] -> WT bf16 [N][K] -------------
__device__ __forceinline__ void tr_tile(const float* __restrict__ W,
                                        bf16* __restrict__ WT,
                                        int K, int N, int n0, int k0, int t) {
    __shared__ float ts[32][33];
    const int r = t >> 3, c4 = (t & 7) * 4;
    const float4 v = *(const float4*)&W[(size_t)(k0 + r) * N + n0 + c4];
    ts[r][c4] = v.x; ts[r][c4 + 1] = v.y; ts[r][c4 + 2] = v.z; ts[r][c4 + 3] = v.w;
    __syncthreads();
    const unsigned u0 = pk2(ts[c4][r], ts[c4 + 1][r]);
    const unsigned u1 = pk2(ts[c4 + 2][r], ts[c4 + 3][r]);
    *(uint2*)&WT[(size_t)(n0 + r) * K + k0 + c4] = make_uint2(u0, u1);
}

// ---- standalone transpose (Wo, launched AFTER attn -> WoT in dead kws) -------
// R14 bug: WoT inside d_out raced with gemm<2>'s full-d_out output write.
// WoT must live in ws; kws (exactly 3.15MB) is dead after attn.
__global__ void __launch_bounds__(256)
tr_w(const float* __restrict__ W, bf16* __restrict__ WT, int K, int N) {
    tr_tile(W, WT, K, N, blockIdx.x * 32, blockIdx.y * 32, threadIdx.x);
}

// ---- prep1: cvt_x (4096 blocks) + Wq (1536) + Wkv (512) ----------------------
__global__ void __launch_bounds__(256)
prep1(const float* __restrict__ x, const float* __restrict__ Wq,
      const float* __restrict__ Wkv, bf16* __restrict__ xb,
      bf16* __restrict__ WqkvT) {
    const int bid = blockIdx.x;
    const int t = threadIdx.x;
    if (bid < 4096) {                           // x fp32 -> bf16, 8/thread
        const size_t i = ((size_t)bid * 256 + t) * 8;
        const float4 a = *(const float4*)&x[i];
        const float4 b = *(const float4*)&x[i + 4];
        uint4 u;
        u.x = pk2(a.x, a.y); u.y = pk2(a.z, a.w);
        u.z = pk2(b.x, b.y); u.w = pk2(b.z, b.w);
        *(uint4*)&xb[i] = u;
    } else if (bid < 5632) {                    // Wq [2048][768] -> WqkvT rows 0-767
        const int l = bid - 4096;
        tr_tile(Wq, WqkvT, Dq, QN, (l % 24) * 32, (l / 24) * 32, t);
    } else {                                    // Wkv [2048][256] -> rows 768-1023
        const int l = bid - 5632;
        tr_tile(Wkv, WqkvT + (size_t)QN * Dq, Dq, LATq, (l % 8) * 32, (l / 8) * 32, t);
    }
}

// ---- prep2: kvrms (1024 blocks) + Wk (96) + Wv (96) --------------------------
// lat = rmsnorm(xkv)*wn, and Wk/Wv -> WkvpT (xb region, dead after gemm<0>).
__global__ void __launch_bounds__(256)
prep2(const float* __restrict__ xkv, const float* __restrict__ wn,
      const float* __restrict__ Wk, const float* __restrict__ Wv,
      bf16* __restrict__ lat, bf16* __restrict__ WkvpT) {
    const int bid = blockIdx.x;
    const int t = threadIdx.x;
    if (bid < 1024) {                           // rmsnorm: 1 wave per row
        const int row = bid * 4 + (t >> 6);
        const int lane = t & 63;
        const float4 v = *(const float4*)&xkv[(size_t)row * LATq + lane * 4];
        float ss = v.x * v.x + v.y * v.y + v.z * v.z + v.w * v.w;
        ss += __shfl_xor(ss, 1);  ss += __shfl_xor(ss, 2);  ss += __shfl_xor(ss, 4);
        ss += __shfl_xor(ss, 8);  ss += __shfl_xor(ss, 16); ss += __shfl_xor(ss, 32);
        const float rr = rsqrtf(ss * (1.0f / LATq) + 1e-5f);
        const float4 g = *(const float4*)&wn[lane * 4];
        const unsigned w0 = pk2(v.x * rr * g.x, v.y * rr * g.y);
        const unsigned w1 = pk2(v.z * rr * g.z, v.w * rr * g.w);
        *(uint2*)&lat[(size_t)row * LATq + lane * 4] = make_uint2(w0, w1);
    } else if (bid < 1120) {                    // Wk [256][384]
        const int l = bid - 1024;
        tr_tile(Wk, WkvpT, LATq, KVN, (l % 12) * 32, (l / 12) * 32, t);
    } else {                                    // Wv [256][384]
        const int l = bid - 1120;
        tr_tile(Wv, WkvpT + (size_t)KVN * LATq, LATq, KVN, (l % 12) * 32, (l / 12) * 32, t);
    }
}

// ==== bf16 GEMM, 128x64 tile, 8 waves, counted-vmcnt pipeline =================
// Mechanism fix for R12/R13 nulls: __syncthreads' vmcnt(0) drain serialized
// every k-step on load latency. lds_barrier() waits lgkm only -> loads issued
// here genuinely stay in flight ~1 full iteration before consumption (per-wave
// FIFO vmcnt gives counted vmcnt(2) waits at each lwrite). k-loop unrolled x2
// with NAMED parity register sets (a0/b0 even-kt, a1/b1 odd-kt; rule #20: no
// runtime-indexed reg arrays). nk even for all MODEs (64/8/24). Geometry:
// 512 thr / 8 waves, wave owns 32x32 (2x2 frags), A staged by 512 thr, B by
// thr<256; LDS 30.7KB, s40 rows.
// Epilogue by MODE (64-col tiles never straddle the split points):
//   0: N=1024 fused qkv  -> col<768: q bf16 [.][768]; else xkv fp32 [.][256]
//   1: N=768  fused k|v  -> col<384: k bf16 [.][384]; else v bf16 [.][384]
//   2: N=2048 oproj      -> fp32 [.][2048]
template<int MODE>
__global__ void __launch_bounds__(512)
gemm128(const bf16* __restrict__ A, const bf16* __restrict__ BT,
        void* __restrict__ C0v, void* __restrict__ C1v, int K) {
    __shared__ short As[2][128 * 40];
    __shared__ short Bs[2][64 * 40];
    const int t  = threadIdx.x;
    const int m0 = blockIdx.x * 128;
    const int n0 = blockIdx.y * 64;
    const int w  = t >> 6;                      // 0..7
    const int wm = (w & 3) * 32;
    const int wn = (w >> 2) * 32;
    const int lr = t & 15;
    const int quad = (t >> 4) & 3;
    const int sr = t >> 2, sc = t & 3;          // staging row / 16B chunk

    f32x4 acc[2][2];
    #pragma unroll
    for (int mi = 0; mi < 2; ++mi)
        #pragma unroll
        for (int ni = 0; ni < 2; ++ni) acc[mi][ni] = (f32x4){0.f, 0.f, 0.f, 0.f};

    int aoff[2], boff[2];
    #pragma unroll
    for (int mi = 0; mi < 2; ++mi) aoff[mi] = (wm + mi * 16 + lr) * 40 + quad * 8;
    #pragma unroll
    for (int ni = 0; ni < 2; ++ni) boff[ni] = (wn + ni * 16 + lr) * 40 + quad * 8;

    uint4 a0, b0, a1, b1;                       // parity register sets
    auto glo0 = [&](int kt) {
        const int kb = kt * 32 + sc * 8;
        a0 = *(const uint4*)&A[(size_t)(m0 + sr) * K + kb];
        if (t < 256) b0 = *(const uint4*)&BT[(size_t)(n0 + sr) * K + kb];
    };
    auto glo1 = [&](int kt) {
        const int kb = kt * 32 + sc * 8;
        a1 = *(const uint4*)&A[(size_t)(m0 + sr) * K + kb];
        if (t < 256) b1 = *(const uint4*)&BT[(size_t)(n0 + sr) * K + kb];
    };
    auto lw0 = [&](int bb) {
        *(uint4*)&As[bb][sr * 40 + sc * 8] = a0;
        if (t < 256) *(uint4*)&Bs[bb][sr * 40 + sc * 8] = b0;
    };
    auto lw1 = [&](int bb) {
        *(uint4*)&As[bb][sr * 40 + sc * 8] = a1;
        if (t < 256) *(uint4*)&Bs[bb][sr * 40 + sc * 8] = b1;
    };
    auto compute = [&](int bb) {
        short8 af[2], bfr[2];
        #pragma unroll
        for (int mi = 0; mi < 2; ++mi) af[mi] = *(const short8*)&As[bb][aoff[mi]];
        #pragma unroll
        for (int ni = 0; ni < 2; ++ni) bfr[ni] = *(const short8*)&Bs[bb][boff[ni]];
        #pragma unroll
        for (int mi = 0; mi < 2; ++mi)
            #pragma unroll
            for (int ni = 0; ni < 2; ++ni)
                acc[mi][ni] = __builtin_amdgcn_mfma_f32_16x16x32_bf16(af[mi], bfr[ni], acc[mi][ni], 0, 0, 0);
    };

    const int nk = K / 32;                      // 64 / 8 / 24 — always even
    glo0(0);
    lw0(0);
    glo1(1);                                    // stays in flight (no drain)
    lds_barrier();
    int cur = 0;

    for (int kt = 0; kt < nk; kt += 2) {
        compute(cur);                           // even step: data parity 0
        if (kt + 2 < nk) glo0(kt + 2);          // overwrites a0 (consumed 2 steps ago)
        lw1(cur ^ 1);                           // kt+1 data, loaded ~1 iter ago
        lds_barrier();
        cur ^= 1;

        compute(cur);                           // odd step: data parity 1
        if (kt + 3 < nk) glo1(kt + 3);
        if (kt + 2 < nk) lw0(cur ^ 1);          // kt+2 data
        lds_barrier();
        cur ^= 1;
    }

    #pragma unroll
    for (int mi = 0; mi < 2; ++mi)
        #pragma unroll
        for (int ni = 0; ni < 2; ++ni) {
            const int col = n0 + wn + ni * 16 + lr;
            #pragma unroll
            for (int r = 0; r < 4; ++r) {
                const int row = m0 + wm + mi * 16 + quad * 4 + r;
                const float v = acc[mi][ni][r];
                if constexpr (MODE == 0) {
                    if (col < QN) ((bf16*)C0v)[(size_t)row * QN + col] = __float2bfloat16(v);
                    else ((float*)C1v)[(size_t)row * LATq + (col - QN)] = v;
                } else if constexpr (MODE == 1) {
                    if (col < KVN) ((bf16*)C0v)[(size_t)row * KVN + col] = __float2bfloat16(v);
                    else ((bf16*)C1v)[(size_t)row * KVN + (col - KVN)] = __float2bfloat16(v);
                } else {
                    ((float*)C0v)[(size_t)row * Dq + col] = v;
                }
            }
        }
}

// ==== MFMA flash attention: 8 waves/block (unchanged, ~68-74 µs) ==============
__global__ void __launch_bounds__(512)
mla_attn(const bf16* __restrict__ q, const bf16* __restrict__ kk,
         const bf16* __restrict__ vv, bf16* __restrict__ ao) {
    __shared__ __align__(16) short Ks[2][64 * 48];
    __shared__ __align__(16) short Vt[2][48 * 72];
    __shared__ __align__(16) short Ps[8][16 * 72];
    const int t    = threadIdx.x;
    const int g    = blockIdx.x;
    const int qy   = blockIdx.y;
    const int b    = blockIdx.z;
    const int qt0  = (qy < 16) ? (qy << 1) : (63 - (qy << 1));
    const int qt   = b ? (31 - qt0) : qt0;
    const int w    = t >> 6;                    // 0..7
    const int lane = t & 63;
    const int lr   = t & 15;
    const int quad = (t >> 4) & 3;
    const int hh   = w & 1;
    const int rh   = w >> 1;                    // 0..3: 16-row subtile
    const int h    = g * 2 + hh;
    const float scale = 0.14433756729740643f;   // 1/sqrt(48)
    const short8 z8 = {0, 0, 0, 0, 0, 0, 0, 0};

    // Q fragment (B-operand): lane holds Q[q = lr][d = ks*32 + quad*8 + j]
    const int qloc = rh * 16 + lr;              // row within the 64-row tile
    const int qg   = qt * 64 + qloc;            // global row
    const bf16* qr = q + (size_t)(b * Tq + qg) * QN + h * HDq;
    short8 qf0 = *(const short8*)(qr + quad * 8);
    const short8 q1 = *(const short8*)(qr + 32 + (quad & 1) * 8);
    short8 qf1 = (quad < 2) ? q1 : z8;

    const bf16* kb = kk + (size_t)b * Tq * KVN + g * HDq;
    const bf16* vb = vv + (size_t)b * Tq * KVN + g * HDq;

    float m = -1e30f, l = 0.f;
    f32x4 acc[3];
    #pragma unroll
    for (int dm = 0; dm < 3; ++dm) acc[dm] = (f32x4){0.f, 0.f, 0.f, 0.f};

    short* Pw = &Ps[w][0];
    uint4 pre[3];

    // staging roles: waves 0,1 -> K (384 uint4 tasks); waves 2,3 -> V^T;
    // waves 4-7 compute-only (wait at barrier while stagers write).
    auto issue = [&](int tl) {
        if (w >= 4) return;
        #pragma unroll
        for (int r = 0; r < 3; ++r) {
            if (w < 2) {
                const int idx = (w * 3 + r) * 64 + lane;
                const int row = idx / 6, ch = idx - row * 6;
                pre[r] = *(const uint4*)(kb + (size_t)(tl * 64 + row) * KVN + ch * 8);
            } else {
                const int idx = ((w - 2) * 3 + r) * 64 + lane;
                const int kp = idx & 31, hc = idx >> 5;
                const bf16* src = vb + (size_t)(tl * 64 + 2 * kp) * KVN + hc * 4;
                const uint2 a2 = *(const uint2*)src;
                const uint2 b2 = *(const uint2*)(src + KVN);
                pre[r].x = a2.x; pre[r].y = a2.y; pre[r].z = b2.x; pre[r].w = b2.y;
            }
        }
    };
    auto lwrite = [&](int bb) {
        if (w >= 4) return;
        #pragma unroll
        for (int r = 0; r < 3; ++r) {
            if (w < 2) {
                const int idx = (w * 3 + r) * 64 + lane;
                const int row = idx / 6, ch = idx - row * 6;
                *(uint4*)&Ks[bb][row * 48 + ch * 8] = pre[r];
            } else {
                const int idx = ((w - 2) * 3 + r) * 64 + lane;
                const int kp = idx & 31, hc = idx >> 5;
                const unsigned short* uu = (const unsigned short*)&pre[r];
                #pragma unroll
                for (int j = 0; j < 4; ++j)
                    *(unsigned*)&Vt[bb][(hc * 4 + j) * 72 + 2 * kp] =
                        (unsigned)uu[j] | ((unsigned)uu[4 + j] << 16);
            }
        }
    };

    issue(0);
    lwrite(0);
    __syncthreads();
    int cur = 0;

    for (int tl = 0; tl <= qt; ++tl) {
        const bool pref = (tl < qt);
        if (pref) issue(tl + 1);

        // S^T[key][q] = K·Q^T : lane holds key = mt*16 + quad*4 + r, q = lr
        f32x4 sc[4];
        #pragma unroll
        for (int mt = 0; mt < 4; ++mt) {
            const short8 k0 = *(const short8*)&Ks[cur][(mt * 16 + lr) * 48 + quad * 8];
            const short8 k1v = *(const short8*)&Ks[cur][(mt * 16 + lr) * 48 + 32 + (quad & 1) * 8];
            const short8 k1 = (quad < 2) ? k1v : z8;
            f32x4 s = (f32x4){0.f, 0.f, 0.f, 0.f};
            s = __builtin_amdgcn_mfma_f32_16x16x32_bf16(k0, qf0, s, 0, 0, 0);
            s = __builtin_amdgcn_mfma_f32_16x16x32_bf16(k1, qf1, s, 0, 0, 0);
            sc[mt] = s;
        }
        if (tl == qt) {                         // diagonal tile: mask key > q
            #pragma unroll
            for (int mt = 0; mt < 4; ++mt)
                #pragma unroll
                for (int r = 0; r < 4; ++r)
                    if (mt * 16 + quad * 4 + r > qloc) sc[mt][r] = -1e30f;
        }
        float mx = -1e30f;
        #pragma unroll
        for (int mt = 0; mt < 4; ++mt)
            #pragma unroll
            for (int r = 0; r < 4; ++r) mx = fmaxf(mx, sc[mt][r]);
        mx = fmaxf(mx, __shfl_xor(mx, 16));
        mx = fmaxf(mx, __shfl_xor(mx, 32));
        const float mn = fmaxf(m, mx * scale);
        const float f  = __expf(m - mn);
        m = mn;
        float rs = 0.f;
        #pragma unroll
        for (int mt = 0; mt < 4; ++mt)
            #pragma unroll
            for (int r = 0; r < 4; ++r) {
                const float p = u2f(f2u(__expf(fmaf(sc[mt][r], scale, -mn))));
                sc[mt][r] = p;                  // bf16-rounded weight
                rs += p;
            }
        rs += __shfl_xor(rs, 16);
        rs += __shfl_xor(rs, 32);
        l = l * f + rs;
        #pragma unroll
        for (int dm = 0; dm < 3; ++dm)
            #pragma unroll
            for (int r = 0; r < 4; ++r) acc[dm][r] *= f;
        // pack P to per-wave scratch: Pw[q=lr][key], key pairs -> u32
        #pragma unroll
        for (int mt = 0; mt < 4; ++mt) {
            unsigned* pw = (unsigned*)&Pw[lr * 72 + mt * 16 + quad * 4];
            pw[0] = pk2(sc[mt][0], sc[mt][1]);
            pw[1] = pk2(sc[mt][2], sc[mt][3]);
        }
        // B-frag read-back: lane holds P[q=lr][key = ks*32 + quad*8 + j]
        const short8 pf0 = *(const short8*)&Pw[lr * 72 + quad * 8];
        const short8 pf1 = *(const short8*)&Pw[lr * 72 + 32 + quad * 8];
        // O^T[d][q] += V^T·P^T : lane accumulates d = dm*16 + quad*4 + r, q = lr
        #pragma unroll
        for (int dm = 0; dm < 3; ++dm) {
            const short8 v0 = *(const short8*)&Vt[cur][(dm * 16 + lr) * 72 + quad * 8];
            const short8 v1 = *(const short8*)&Vt[cur][(dm * 16 + lr) * 72 + 32 + quad * 8];
            acc[dm] = __builtin_amdgcn_mfma_f32_16x16x32_bf16(v0, pf0, acc[dm], 0, 0, 0);
            acc[dm] = __builtin_amdgcn_mfma_f32_16x16x32_bf16(v1, pf1, acc[dm], 0, 0, 0);
        }

        if (pref) lwrite(cur ^ 1);              // overlapped with compute
        __syncthreads();
        cur ^= 1;
    }

    const float inv = 1.0f / l;
    bf16* orow = ao + (size_t)(b * Tq + qg) * QN + h * HDq;
    #pragma unroll
    for (int dm = 0; dm < 3; ++dm) {
        const unsigned w0 = pk2(acc[dm][0] * inv, acc[dm][1] * inv);
        const unsigned w1 = pk2(acc[dm][2] * inv, acc[dm][3] * inv);
        *(uint2*)(orow + dm * 16 + quad * 4) = make_uint2(w0, w1);
    }
}

extern "C" void kernel_launch(void* const* d_in, const int* in_sizes, int n_in,
                              void* d_out, int out_size, void* d_ws, size_t ws_size,
                              hipStream_t stream) {
    const float* x   = (const float*)d_in[0];
    // d_in[1]: causal mask — static tril, applied analytically in mla_attn
    const float* Wq  = (const float*)d_in[2];
    const float* Wkv = (const float*)d_in[3];
    const float* wn  = (const float*)d_in[4];
    const float* Wk  = (const float*)d_in[5];
    const float* Wv  = (const float*)d_in[6];
    const float* Wo  = (const float*)d_in[7];
    float* out = (float*)d_out;

    const int M = Bq * Tq;                          // 4096
    // d_out staging (all dead before oproj's final write; 33,554,432 B):
    //   [0        : 16.78M)  xb     bf16 [4096 x 2048]  (dead after gemm<0>;
    //                        WkvpT bf16 [768 x 256] overwrites it in prep2)
    //   [16.78M   : 23.07M)  q      bf16 [4096 x 768]
    //   [27.26M   : 29.36M)  lat    bf16 [4096 x 256]
    //   [29.36M   : 33.55M)  WqkvT  bf16 [1024 x 2048]  (rows 0-767 Wq, 768+ Wkv)
    // ws: k 3.15M | v 3.15M | ao 6.29M.
    //   xkv fp32 [4096 x 256] (4.19M) lives in the ao region until prep2
    //   consumes it (attn overwrites ao afterwards).
    //   WoT bf16 [2048 x 768] (3.15M) overwrites kws AFTER attn (last k reader)
    //   — NEVER in d_out: gemm<2> writes all of d_out while reading WoT (R14's
    //   NaN was exactly that race).
    char* ob = (char*)d_out;
    bf16*  xb    = (bf16*)ob;
    bf16*  WkvpT = (bf16*)ob;                       // after gemm<0>
    bf16*  qws   = (bf16*)(ob + 16777216);
    bf16*  latb  = (bf16*)(ob + 27262976);
    bf16*  WqkvT = (bf16*)(ob + 29360128);
    bf16*  kws = (bf16*)d_ws;
    bf16*  vws = kws + (size_t)M * KVN;
    bf16*  aob = vws + (size_t)M * KVN;
    float* xkv = (float*)aob;                       // dead before attn writes ao
    bf16*  WoT = kws;                               // after attn (kws dead)

    prep1 <<<6144, 256, 0, stream>>>(x, Wq, Wkv, xb, WqkvT);
    gemm128<0> <<<dim3(M / 128, 1024 / 64), 512, 0, stream>>>(xb, WqkvT, qws, xkv, Dq);
    prep2 <<<1216, 256, 0, stream>>>(xkv, wn, Wk, Wv, latb, WkvpT);
    gemm128<1> <<<dim3(M / 128, 768 / 64), 512, 0, stream>>>(latb, WkvpT, kws, vws, LATq);
    mla_attn <<<dim3(NLHq, 32, Bq), 512, 0, stream>>>(qws, kws, vws, aob);
    tr_w <<<dim3(Dq / 32, QN / 32), 256, 0, stream>>>(Wo, WoT, QN, Dq);
    gemm128<2> <<<dim3(M / 128, Dq / 64), 512, 0, stream>>>(aob, WoT, out, nullptr, QN);
}